// Round 2
// baseline (492.584 us; speedup 1.0000x reference)
//
#include <hip/hip_runtime.h>
#include <hip/hip_bf16.h>
#include <cmath>

#define B_ 2
#define H_ 16
#define S_ 2048
#define D_ 64
// padded LDS row stride (bf16 elems): 2056*2B = 4112B = 257*16 -> 16B-aligned rows,
// and (lane&15)*1028 dwords % 32 banks = 8 distinct banks -> 2-way (free)
#define PSTR 2056

typedef float f32x4 __attribute__((ext_vector_type(4)));
typedef short s16x8 __attribute__((ext_vector_type(8)));

__device__ __forceinline__ short f2bf(float f) {
  unsigned u = __float_as_uint(f);
  u += 0x7FFFu + ((u >> 16) & 1u);   // RTNE (inputs are finite)
  return (short)(u >> 16);
}
__device__ __forceinline__ float bf2f(short s) {
  return __uint_as_float(((unsigned)(unsigned short)s) << 16);
}

__launch_bounds__(256, 2)
__global__ void attend_kernel(const float* __restrict__ q,
                              const float* __restrict__ k,
                              const float* __restrict__ v,
                              const int* __restrict__ mask,
                              float* __restrict__ out,
                              float* __restrict__ attn) {
  __shared__ short ps[16 * PSTR];     // 16 q-rows x 2048 j, bf16 P-strip (~66KB)
  __shared__ float ls_rs[4][16];      // per-wave row-sum partials
  __shared__ float ls_rinv[16];       // 1 / rowsum

  const int tid  = threadIdx.x;
  const int wv   = tid >> 6;          // wave 0..3
  const int lane = tid & 63;
  const int lg   = lane >> 4;         // 16-lane group 0..3
  const int li   = lane & 15;

  const int q0 = blockIdx.x * 16;     // q-tile base
  const int bh = blockIdx.y;          // b*H + h
  const int b  = bh >> 4;

  const float* qh = q + (size_t)bh * S_ * D_;
  const float* kh = k + (size_t)bh * S_ * D_;
  const float* vh = v + (size_t)bh * S_ * D_;
  const int* mrow = mask + (size_t)b * S_;

  // ---- Q A-fragments: lane holds Q[q0+li][ks*32 + lg*8 + e], e=0..7 ----
  s16x8 qf[2];
  {
    const float* qr = qh + (size_t)(q0 + li) * D_ + lg * 8;
    #pragma unroll
    for (int ks = 0; ks < 2; ++ks) {
      #pragma unroll
      for (int e = 0; e < 8; ++e) qf[ks][e] = f2bf(qr[ks * 32 + e]);
    }
  }

  // ---- Phase 1: S = QK^T, softcap, mask, p = exp(sc-50); fill P-strip ----
  float rs[4] = {0.f, 0.f, 0.f, 0.f};

  for (int c = wv; c < S_ / 64; c += 4) {   // each wave owns 64-j chunks
    const int jc = c * 64;
    f32x4 acc[4];
    #pragma unroll
    for (int n = 0; n < 4; ++n) acc[n] = (f32x4){0.f, 0.f, 0.f, 0.f};

    #pragma unroll
    for (int n = 0; n < 4; ++n) {
      // B-fragment: lane holds K[jc + n*16 + li][ks*32 + lg*8 + e]
      const float* kr = kh + (size_t)(jc + n * 16 + li) * D_ + lg * 8;
      #pragma unroll
      for (int ks = 0; ks < 2; ++ks) {
        s16x8 kf;
        #pragma unroll
        for (int e = 0; e < 8; ++e) kf[e] = f2bf(kr[ks * 32 + e]);
        acc[n] = __builtin_amdgcn_mfma_f32_16x16x32_bf16(qf[ks], kf, acc[n], 0, 0, 0);
      }
    }

    #pragma unroll
    for (int n = 0; n < 4; ++n) {
      const int j = jc + n * 16 + li;          // D col = lane&15
      const bool keep = mrow[j] != 0;
      #pragma unroll
      for (int r = 0; r < 4; ++r) {            // D row = lg*4 + r
        float s = acc[n][r] * 0.125f;          // * D^-0.5
        // softcap+exp fused: p = exp(50*tanh(s/50) - 50) = exp(-100/(e^{2s/50}+1))
        float t = exp2f(s * 0.057707802f);     // e^{2s/50}
        float p = exp2f(-144.269504f * __builtin_amdgcn_rcpf(t + 1.f));
        p = keep ? p : 0.f;
        rs[r] += p;
        ps[(lg * 4 + r) * PSTR + j] = f2bf(p);
      }
    }
  }

  // ---- row sums: reduce over the 16 lanes of each lg group, then waves ----
  #pragma unroll
  for (int r = 0; r < 4; ++r) {
    #pragma unroll
    for (int m = 1; m < 16; m <<= 1) rs[r] += __shfl_xor(rs[r], m, 64);
  }
  if (li == 0) {
    #pragma unroll
    for (int r = 0; r < 4; ++r) ls_rs[wv][lg * 4 + r] = rs[r];
  }
  __syncthreads();
  if (tid < 16) {
    float s = ls_rs[0][tid] + ls_rs[1][tid] + ls_rs[2][tid] + ls_rs[3][tid];
    ls_rinv[tid] = (s > 0.f) ? 1.f / s : 0.f;
  }
  __syncthreads();

  // ---- Phase 2a: write normalized attn (coalesced float4 x2 per thread) ----
  {
    float* abase = attn + ((size_t)bh * S_ + q0) * S_;
    #pragma unroll 4
    for (int qq = 0; qq < 16; ++qq) {
      const float ri = ls_rinv[qq];
      s16x8 pv = *(const s16x8*)&ps[qq * PSTR + tid * 8];
      float4 a0, a1;
      a0.x = bf2f(pv[0]) * ri; a0.y = bf2f(pv[1]) * ri;
      a0.z = bf2f(pv[2]) * ri; a0.w = bf2f(pv[3]) * ri;
      a1.x = bf2f(pv[4]) * ri; a1.y = bf2f(pv[5]) * ri;
      a1.z = bf2f(pv[6]) * ri; a1.w = bf2f(pv[7]) * ri;
      float4* ap = (float4*)(abase + (size_t)qq * S_ + tid * 8);
      ap[0] = a0; ap[1] = a1;
    }
  }

  // ---- Phase 2b: out = (P V) * rinv; wave w owns d-chunk [w*16, w*16+16) ----
  {
    const int d0 = wv * 16;
    f32x4 oacc = (f32x4){0.f, 0.f, 0.f, 0.f};
    #pragma unroll 2
    for (int jc = 0; jc < S_; jc += 32) {
      // A-frag: P[li][jc + lg*8 + e] from LDS (16B aligned)
      s16x8 pa = *(const s16x8*)&ps[li * PSTR + jc + lg * 8];
      // B-frag: V[jc + lg*8 + e][d0 + li] (16-lane groups form 64B segments)
      s16x8 vb;
      const float* vp = vh + (size_t)(jc + lg * 8) * D_ + d0 + li;
      #pragma unroll
      for (int e = 0; e < 8; ++e) vb[e] = f2bf(vp[(size_t)e * D_]);
      oacc = __builtin_amdgcn_mfma_f32_16x16x32_bf16(pa, vb, oacc, 0, 0, 0);
    }
    #pragma unroll
    for (int r = 0; r < 4; ++r) {
      const int qq = lg * 4 + r;
      out[((size_t)bh * S_ + q0 + qq) * D_ + d0 + li] = oacc[r] * ls_rinv[qq];
    }
  }
}

extern "C" void kernel_launch(void* const* d_in, const int* in_sizes, int n_in,
                              void* d_out, int out_size, void* d_ws, size_t ws_size,
                              hipStream_t stream) {
  const float* q = (const float*)d_in[0];
  const float* k = (const float*)d_in[1];
  const float* v = (const float*)d_in[2];
  const int* mask = (const int*)d_in[3];

  float* out  = (float*)d_out;
  float* attn = out + (size_t)B_ * H_ * S_ * D_;

  dim3 grid(S_ / 16, B_ * H_);
  attend_kernel<<<grid, 256, 0, stream>>>(q, k, v, mask, out, attn);
}

// Round 4
// 332.496 us; speedup vs baseline: 1.4815x; 1.4815x over previous
//
#include <hip/hip_runtime.h>
#include <hip/hip_bf16.h>

#define B_ 2
#define H_ 16
#define S_ 2048
#define D_ 64
#define PSTR 2056   // bf16 elems; 4112B rows -> 16B aligned, benign bank layout

typedef float f32x4 __attribute__((ext_vector_type(4)));
typedef short s16x8 __attribute__((ext_vector_type(8)));

__device__ __forceinline__ short f2bf(float f) {
  unsigned u = __float_as_uint(f);
  u += 0x7FFFu + ((u >> 16) & 1u);   // RTNE (finite inputs)
  return (short)(u >> 16);
}
__device__ __forceinline__ float bf2f(short s) {
  return __uint_as_float(((unsigned)(unsigned short)s) << 16);
}

// ---------------- prep: f32 -> bf16 (Q, K) ----------------
__global__ __launch_bounds__(256) void prep_qk(const float* __restrict__ q,
                                               const float* __restrict__ k,
                                               short* __restrict__ qbf,
                                               short* __restrict__ kbf) {
  size_t i = ((size_t)blockIdx.x * 256 + threadIdx.x) * 8;
  const f32x4* qa = (const f32x4*)(q + i);
  const f32x4* ka = (const f32x4*)(k + i);
  f32x4 a0 = __builtin_nontemporal_load(qa);
  f32x4 a1 = __builtin_nontemporal_load(qa + 1);
  f32x4 b0 = __builtin_nontemporal_load(ka);
  f32x4 b1 = __builtin_nontemporal_load(ka + 1);
  s16x8 oq, ok;
  #pragma unroll
  for (int e = 0; e < 4; ++e) {
    oq[e] = f2bf(a0[e]); oq[4 + e] = f2bf(a1[e]);
    ok[e] = f2bf(b0[e]); ok[4 + e] = f2bf(b1[e]);
  }
  *(s16x8*)(qbf + i) = oq;
  *(s16x8*)(kbf + i) = ok;
}

// ---------------- prep: V -> bf16 transposed Vt[bh][d][j] ----------------
__global__ __launch_bounds__(256) void prep_v(const float* __restrict__ v,
                                              short* __restrict__ vt) {
  __shared__ float tile[64][65];
  const int tid = threadIdx.x;
  const int j0 = blockIdx.x * 64;
  const int bh = blockIdx.y;
  const float* vh = v + (size_t)bh * S_ * D_;
  #pragma unroll
  for (int it = 0; it < 16; ++it) {
    int idx = it * 256 + tid;
    int row = idx >> 6, col = idx & 63;
    tile[row][col] = __builtin_nontemporal_load(&vh[(size_t)(j0 + row) * D_ + col]);
  }
  __syncthreads();
  short* vth = vt + (size_t)bh * D_ * S_;
  #pragma unroll
  for (int it = 0; it < 16; ++it) {
    int idx = it * 256 + tid;
    int d = idx >> 6, jj = idx & 63;
    vth[(size_t)d * S_ + j0 + jj] = f2bf(tile[jj][d]);
  }
}

// ---------------- main fused kernel ----------------
template <bool PRE>
__global__ __launch_bounds__(512, 4) void attend_kernel(
    const float* __restrict__ q, const float* __restrict__ k,
    const float* __restrict__ v, const int* __restrict__ mask,
    const short* __restrict__ qbf, const short* __restrict__ kbf,
    const short* __restrict__ vt,
    float* __restrict__ out, float* __restrict__ attn) {
  __shared__ short ps[16 * PSTR];   // 16 q-rows x 2048 j bf16 P-strip (~64KB)
  __shared__ float ls_rs[8][16];
  __shared__ float ls_rinv[16];

  const int tid  = threadIdx.x;
  const int wv   = tid >> 6;        // wave 0..7
  const int lane = tid & 63;
  const int lg   = lane >> 4;
  const int li   = lane & 15;

  const int q0 = blockIdx.x * 16;
  const int bh = blockIdx.y;
  const int b  = bh >> 4;
  const int* mrow = mask + (size_t)b * S_;

  // Q A-fragment: lane holds Q[q0+li][ks*32 + lg*8 + e]
  s16x8 qf[2];
  if constexpr (PRE) {
    const short* qr = qbf + ((size_t)bh * S_ + q0 + li) * D_ + lg * 8;
    qf[0] = *(const s16x8*)qr;
    qf[1] = *(const s16x8*)(qr + 32);
  } else {
    const float* qr = q + ((size_t)bh * S_ + q0 + li) * D_ + lg * 8;
    #pragma unroll
    for (int ks = 0; ks < 2; ++ks)
      #pragma unroll
      for (int e = 0; e < 8; ++e) qf[ks][e] = f2bf(qr[ks * 32 + e]);
  }

  // ---- Phase 1: QK^T + fused softcap-exp, fill P-strip, row sums ----
  float rs[4] = {0.f, 0.f, 0.f, 0.f};

  for (int c = wv; c < S_ / 64; c += 8) {   // 4 chunks of 64 j per wave
    const int jc = c * 64;
    f32x4 acc[4];
    #pragma unroll
    for (int n = 0; n < 4; ++n) acc[n] = (f32x4){0.f, 0.f, 0.f, 0.f};

    #pragma unroll
    for (int n = 0; n < 4; ++n) {
      if constexpr (PRE) {
        const short* kr = kbf + ((size_t)bh * S_ + jc + n * 16 + li) * D_ + lg * 8;
        acc[n] = __builtin_amdgcn_mfma_f32_16x16x32_bf16(qf[0], *(const s16x8*)kr, acc[n], 0, 0, 0);
        acc[n] = __builtin_amdgcn_mfma_f32_16x16x32_bf16(qf[1], *(const s16x8*)(kr + 32), acc[n], 0, 0, 0);
      } else {
        const float* kr = k + ((size_t)bh * S_ + jc + n * 16 + li) * D_ + lg * 8;
        s16x8 kf0, kf1;
        #pragma unroll
        for (int e = 0; e < 8; ++e) { kf0[e] = f2bf(kr[e]); kf1[e] = f2bf(kr[32 + e]); }
        acc[n] = __builtin_amdgcn_mfma_f32_16x16x32_bf16(qf[0], kf0, acc[n], 0, 0, 0);
        acc[n] = __builtin_amdgcn_mfma_f32_16x16x32_bf16(qf[1], kf1, acc[n], 0, 0, 0);
      }
    }

    #pragma unroll
    for (int n = 0; n < 4; ++n) {
      const int j = jc + n * 16 + li;
      const bool keep = mrow[j] != 0;
      #pragma unroll
      for (int r = 0; r < 4; ++r) {
        float s = acc[n][r] * 0.125f;
        // p = exp(50*tanh(s/50) - 50) = exp(-100/(e^{2s/50}+1))
        float t = exp2f(s * 0.057707802f);
        float p = exp2f(-144.269504f * __builtin_amdgcn_rcpf(t + 1.f));
        p = keep ? p : 0.f;
        rs[r] += p;
        ps[(lg * 4 + r) * PSTR + j] = f2bf(p);
      }
    }
  }

  // row-sum reduce: 16 lanes within lg group, then across 8 waves via LDS
  #pragma unroll
  for (int r = 0; r < 4; ++r) {
    #pragma unroll
    for (int m = 1; m < 16; m <<= 1) rs[r] += __shfl_xor(rs[r], m, 64);
  }
  if (li == 0) {
    #pragma unroll
    for (int r = 0; r < 4; ++r) ls_rs[wv][lg * 4 + r] = rs[r];
  }
  __syncthreads();
  if (tid < 16) {
    float ssum = 0.f;
    #pragma unroll
    for (int w = 0; w < 8; ++w) ssum += ls_rs[w][tid];
    ls_rinv[tid] = (ssum > 0.f) ? 1.f / ssum : 0.f;
  }
  __syncthreads();

  if (wv < 4) {
    // ---- Phase 2a (waves 0-3): stream normalized attn, non-temporal ----
    float* abase = attn + ((size_t)bh * S_ + q0) * S_;
    #pragma unroll 4
    for (int qq = 0; qq < 16; ++qq) {
      const float ri = ls_rinv[qq];
      s16x8 pv = *(const s16x8*)&ps[qq * PSTR + tid * 8];
      f32x4 a0, a1;
      a0[0] = bf2f(pv[0]) * ri; a0[1] = bf2f(pv[1]) * ri;
      a0[2] = bf2f(pv[2]) * ri; a0[3] = bf2f(pv[3]) * ri;
      a1[0] = bf2f(pv[4]) * ri; a1[1] = bf2f(pv[5]) * ri;
      a1[2] = bf2f(pv[6]) * ri; a1[3] = bf2f(pv[7]) * ri;
      f32x4* ap = (f32x4*)(abase + (size_t)qq * S_ + tid * 8);
      __builtin_nontemporal_store(a0, ap);
      __builtin_nontemporal_store(a1, ap + 1);
    }
  } else {
    // ---- Phase 2b (waves 4-7): out = (P V) * rinv, d-chunk per wave ----
    const int d0 = (wv - 4) * 16;
    f32x4 oa = (f32x4){0.f, 0.f, 0.f, 0.f};
    f32x4 ob = (f32x4){0.f, 0.f, 0.f, 0.f};
    if constexpr (PRE) {
      const short* vrow = vt + ((size_t)bh * D_ + d0 + li) * S_;
      #pragma unroll 2
      for (int jc = 0; jc < S_; jc += 64) {
        s16x8 pa0 = *(const s16x8*)&ps[li * PSTR + jc + lg * 8];
        s16x8 pa1 = *(const s16x8*)&ps[li * PSTR + jc + 32 + lg * 8];
        s16x8 vb0 = *(const s16x8*)(vrow + jc + lg * 8);
        s16x8 vb1 = *(const s16x8*)(vrow + jc + 32 + lg * 8);
        oa = __builtin_amdgcn_mfma_f32_16x16x32_bf16(pa0, vb0, oa, 0, 0, 0);
        ob = __builtin_amdgcn_mfma_f32_16x16x32_bf16(pa1, vb1, ob, 0, 0, 0);
      }
    } else {
      const float* vp0 = v + (size_t)bh * S_ * D_ + d0 + li;
      for (int jc = 0; jc < S_; jc += 32) {
        s16x8 pa = *(const s16x8*)&ps[li * PSTR + jc + lg * 8];
        s16x8 vb;
        const float* vp = vp0 + (size_t)(jc + lg * 8) * D_;
        #pragma unroll
        for (int e = 0; e < 8; ++e) vb[e] = f2bf(vp[(size_t)e * D_]);
        oa = __builtin_amdgcn_mfma_f32_16x16x32_bf16(pa, vb, oa, 0, 0, 0);
      }
    }
    #pragma unroll
    for (int r = 0; r < 4; ++r) {
      const int qq = lg * 4 + r;
      out[((size_t)bh * S_ + q0 + qq) * D_ + d0 + li] = (oa[r] + ob[r]) * ls_rinv[qq];
    }
  }
}

extern "C" void kernel_launch(void* const* d_in, const int* in_sizes, int n_in,
                              void* d_out, int out_size, void* d_ws, size_t ws_size,
                              hipStream_t stream) {
  const float* q = (const float*)d_in[0];
  const float* k = (const float*)d_in[1];
  const float* v = (const float*)d_in[2];
  const int* mask = (const int*)d_in[3];

  float* out  = (float*)d_out;
  const size_t nel = (size_t)B_ * H_ * S_ * D_;
  float* attn = out + nel;

  dim3 grid(S_ / 16, B_ * H_);
  const size_t need = nel * 2 * 3;   // Qbf + Kbf + Vt, bf16

  if (ws_size >= need) {
    short* qbf = (short*)d_ws;
    short* kbf = qbf + nel;
    short* vtp = kbf + nel;
    prep_qk<<<(int)(nel / (256 * 8)), 256, 0, stream>>>(q, k, qbf, kbf);
    prep_v<<<dim3(S_ / 64, B_ * H_), 256, 0, stream>>>(v, vtp);
    attend_kernel<true><<<grid, 512, 0, stream>>>(q, k, v, mask, qbf, kbf, vtp, out, attn);
  } else {
    attend_kernel<false><<<grid, 512, 0, stream>>>(q, k, v, mask, nullptr, nullptr, nullptr, out, attn);
  }
}